// Round 2
// baseline (931.323 us; speedup 1.0000x reference)
//
#include <hip/hip_runtime.h>
#include <hip/hip_bf16.h>

#define N_FEAT 128
#define DIM 128
#define N_GRAPHS 128
#define BN_EPS 1e-5f

// ---------------- preprocessing ----------------

__global__ void hist_kernel(const int* __restrict__ dst, int* __restrict__ cnt, int E) {
    int i = blockIdx.x * blockDim.x + threadIdx.x;
    if (i < E) atomicAdd(&cnt[dst[i]], 1);
}

__global__ void dinv_kernel(const int* __restrict__ cnt, float* __restrict__ dinv, int N) {
    int i = blockIdx.x * blockDim.x + threadIdx.x;
    if (i < N) dinv[i] = rsqrtf((float)(cnt[i] + 1));   // +1 self loop, always > 0
}

// exclusive scan, hierarchical (256 per block)
__global__ void scan_partial(const int* __restrict__ cnt, int* __restrict__ out,
                             int* __restrict__ bsums, int n) {
    __shared__ int tmp[256];
    int tid = threadIdx.x;
    int gid = blockIdx.x * 256 + tid;
    int v = (gid < n) ? cnt[gid] : 0;
    tmp[tid] = v;
    __syncthreads();
    for (int off = 1; off < 256; off <<= 1) {
        int t = (tid >= off) ? tmp[tid - off] : 0;
        __syncthreads();
        tmp[tid] += t;
        __syncthreads();
    }
    if (gid < n) out[gid] = tmp[tid] - v;     // exclusive
    if (tid == 255) bsums[blockIdx.x] = tmp[255];
}

__global__ void scan_bsums(int* __restrict__ bsums, int nb) {
    __shared__ int tmp[256];
    int tid = threadIdx.x;
    int v = (tid < nb) ? bsums[tid] : 0;
    tmp[tid] = v;
    __syncthreads();
    for (int off = 1; off < 256; off <<= 1) {
        int t = (tid >= off) ? tmp[tid - off] : 0;
        __syncthreads();
        tmp[tid] += t;
        __syncthreads();
    }
    if (tid < nb) bsums[tid] = tmp[tid] - v;  // exclusive
}

__global__ void scan_add(int* __restrict__ out, const int* __restrict__ bsums, int n) {
    int gid = blockIdx.x * 256 + threadIdx.x;
    if (gid < n) out[gid] += bsums[blockIdx.x];
}

__global__ void fill_csr(const int* __restrict__ src, const int* __restrict__ dst,
                         const int* __restrict__ rowp, int* __restrict__ fill,
                         int* __restrict__ csr, int E) {
    int i = blockIdx.x * blockDim.x + threadIdx.x;
    if (i < E) {
        int dv = dst[i];
        int pos = rowp[dv] + atomicAdd(&fill[dv], 1);
        csr[pos] = src[i];
    }
}

// ---------------- GEMM: C[N,128] = A[N,128] @ W[128,128] ----------------
__global__ __launch_bounds__(256) void gemm128(const float* __restrict__ A,
                                               const float* __restrict__ W,
                                               float* __restrict__ C, int N) {
    __shared__ float As[64][132];
    __shared__ float Ws[128][132];
    int tid = threadIdx.x;
    int row0 = blockIdx.x * 64;

    for (int i = tid; i < 128 * 32; i += 256) {       // W: 16384 floats as float4
        int r = i >> 5, c = (i & 31) << 2;
        float4 w = *(const float4*)(W + r * 128 + c);
        Ws[r][c] = w.x; Ws[r][c + 1] = w.y; Ws[r][c + 2] = w.z; Ws[r][c + 3] = w.w;
    }
    for (int i = tid; i < 64 * 32; i += 256) {        // A tile
        int r = i >> 5, c = (i & 31) << 2;
        int gr = row0 + r;
        float4 a = make_float4(0.f, 0.f, 0.f, 0.f);
        if (gr < N) a = *(const float4*)(A + (size_t)gr * 128 + c);
        As[r][c] = a.x; As[r][c + 1] = a.y; As[r][c + 2] = a.z; As[r][c + 3] = a.w;
    }
    __syncthreads();

    int ty = tid >> 4, tx = tid & 15;                 // 16x16 threads, 4x8 micro-tile
    float acc[4][8] = {};
    for (int k = 0; k < 128; ++k) {
        float a0 = As[ty * 4 + 0][k];
        float a1 = As[ty * 4 + 1][k];
        float a2 = As[ty * 4 + 2][k];
        float a3 = As[ty * 4 + 3][k];
        float b[8];
#pragma unroll
        for (int j = 0; j < 8; ++j) b[j] = Ws[k][tx * 8 + j];
#pragma unroll
        for (int j = 0; j < 8; ++j) {
            acc[0][j] = fmaf(a0, b[j], acc[0][j]);
            acc[1][j] = fmaf(a1, b[j], acc[1][j]);
            acc[2][j] = fmaf(a2, b[j], acc[2][j]);
            acc[3][j] = fmaf(a3, b[j], acc[3][j]);
        }
    }
#pragma unroll
    for (int i = 0; i < 4; ++i) {
        int gr = row0 + ty * 4 + i;
        if (gr < N) {
            float4* p = (float4*)(C + (size_t)gr * 128 + tx * 8);
            p[0] = make_float4(acc[i][0], acc[i][1], acc[i][2], acc[i][3]);
            p[1] = make_float4(acc[i][4], acc[i][5], acc[i][6], acc[i][7]);
        }
    }
}

// ---------------- aggregation + bias + relu (one block per node) ----------------
__global__ __launch_bounds__(128) void agg_relu(const float* __restrict__ hW,
                                                const int* __restrict__ rowp,
                                                const int* __restrict__ cnt,
                                                const int* __restrict__ csr,
                                                const float* __restrict__ dinv,
                                                const float* __restrict__ bias,
                                                float* __restrict__ z, int N) {
    int v = blockIdx.x;
    int d = threadIdx.x;
    int beg = rowp[v];
    int num = cnt[v];
    float s = 0.f;
    int i = 0;
    for (; i + 4 <= num; i += 4) {
        int u0 = csr[beg + i + 0];
        int u1 = csr[beg + i + 1];
        int u2 = csr[beg + i + 2];
        int u3 = csr[beg + i + 3];
        float w0 = dinv[u0], w1 = dinv[u1], w2 = dinv[u2], w3 = dinv[u3];
        float h0 = hW[(size_t)u0 * 128 + d];
        float h1 = hW[(size_t)u1 * 128 + d];
        float h2 = hW[(size_t)u2 * 128 + d];
        float h3 = hW[(size_t)u3 * 128 + d];
        s += w0 * h0 + w1 * h1 + w2 * h2 + w3 * h3;
    }
    for (; i < num; ++i) {
        int u = csr[beg + i];
        s += dinv[u] * hW[(size_t)u * 128 + d];
    }
    float dv = dinv[v];
    float val = dv * s + dv * dv * hW[(size_t)v * 128 + d] + bias[d];
    z[(size_t)v * 128 + d] = fmaxf(val, 0.f);
}

// ---------------- BN statistics ----------------
__global__ __launch_bounds__(256) void bn_stats(const float* __restrict__ z,
                                                float* __restrict__ stats, int N) {
    int d = threadIdx.x & 127;
    int half = threadIdx.x >> 7;
    float sum = 0.f, sq = 0.f;
    for (int v = blockIdx.x * 2 + half; v < N; v += gridDim.x * 2) {
        float x = z[(size_t)v * 128 + d];
        sum += x;
        sq = fmaf(x, x, sq);
    }
    __shared__ float ls[256], lq[256];
    ls[threadIdx.x] = sum;
    lq[threadIdx.x] = sq;
    __syncthreads();
    if (half == 0) {
        atomicAdd(&stats[d], ls[threadIdx.x] + ls[threadIdx.x + 128]);
        atomicAdd(&stats[128 + d], lq[threadIdx.x] + lq[threadIdx.x + 128]);
    }
}

__global__ void bn_finalize(const float* __restrict__ stats, const float* __restrict__ g,
                            const float* __restrict__ be, float* __restrict__ ss, float invN) {
    int d = threadIdx.x;  // 128 threads
    float mu = stats[d] * invN;
    float var = stats[128 + d] * invN - mu * mu;
    float sc = g[d] * rsqrtf(var + BN_EPS);
    ss[d] = sc;
    ss[128 + d] = be[d] - mu * sc;
}

// ---------------- apply BN (in place) + pooled segment sum ----------------
__global__ __launch_bounds__(128) void apply_pool(float* __restrict__ z,
                                                  const float* __restrict__ ss,
                                                  const int* __restrict__ batch,
                                                  float* __restrict__ out,
                                                  int layer, int N) {
    __shared__ int gb[128];
    int d = threadIdx.x;
    int v0 = blockIdx.x * 128;
    int vend = min(v0 + 128, N);
    int cnt = vend - v0;
    if (d < cnt) gb[d] = batch[v0 + d];
    __syncthreads();

    float sc = ss[d], sh = ss[128 + d];
    float acc = 0.f;
    int cur = gb[0];
    for (int j = 0; j < cnt; ++j) {
        int g = gb[j];
        float val = fmaf(z[(size_t)(v0 + j) * 128 + d], sc, sh);
        z[(size_t)(v0 + j) * 128 + d] = val;
        if (g != cur) {
            atomicAdd(&out[(size_t)cur * 384 + layer * 128 + d], acc);
            acc = 0.f;
            cur = g;
        }
        acc += val;
    }
    atomicAdd(&out[(size_t)cur * 384 + layer * 128 + d], acc);
}

// ---------------- launch ----------------
extern "C" void kernel_launch(void* const* d_in, const int* in_sizes, int n_in,
                              void* d_out, int out_size, void* d_ws, size_t ws_size,
                              hipStream_t stream) {
    const float* x    = (const float*)d_in[0];
    const int* eidx   = (const int*)d_in[1];
    const int* batch  = (const int*)d_in[2];

    const int N = in_sizes[2];          // 50000
    const int E = in_sizes[1] / 2;      // 1600000
    const int* src = eidx;
    const int* dst = eidx + E;

    // workspace layout
    size_t off = 0;
    auto alloc = [&](size_t bytes) {
        void* p = (char*)d_ws + off;
        off += (bytes + 255) & ~(size_t)255;
        return p;
    };
    float* hW   = (float*)alloc((size_t)N * 128 * 4);
    float* hbuf = (float*)alloc((size_t)N * 128 * 4);
    int*   csr  = (int*)alloc((size_t)E * 4);
    int*   deg  = (int*)alloc((size_t)N * 4);
    int*   rowp = (int*)alloc((size_t)N * 4);
    int*   fill = (int*)alloc((size_t)N * 4);
    float* dinv = (float*)alloc((size_t)N * 4);
    int*   bsums = (int*)alloc(1024);
    float* stats = (float*)alloc(3 * 256 * 4);
    float* ss    = (float*)alloc(3 * 256 * 4);

    float* out = (float*)d_out;

    hipMemsetAsync(deg, 0, (size_t)N * 4, stream);
    hipMemsetAsync(fill, 0, (size_t)N * 4, stream);
    hipMemsetAsync(stats, 0, 3 * 256 * 4, stream);
    hipMemsetAsync(out, 0, (size_t)N_GRAPHS * 384 * 4, stream);

    int nb = (N + 255) / 256;   // 196
    hist_kernel<<<(E + 255) / 256, 256, 0, stream>>>(dst, deg, E);
    dinv_kernel<<<nb, 256, 0, stream>>>(deg, dinv, N);
    scan_partial<<<nb, 256, 0, stream>>>(deg, rowp, bsums, N);
    scan_bsums<<<1, 256, 0, stream>>>(bsums, nb);
    scan_add<<<nb, 256, 0, stream>>>(rowp, bsums, N);
    fill_csr<<<(E + 255) / 256, 256, 0, stream>>>(src, dst, rowp, fill, csr, E);

    const int gemm_blocks = (N + 63) / 64;
    const int pool_blocks = (N + 127) / 128;

    for (int l = 0; l < 3; ++l) {
        const float* W  = (const float*)d_in[3 + 4 * l];
        const float* b  = (const float*)d_in[4 + 4 * l];
        const float* g  = (const float*)d_in[5 + 4 * l];
        const float* be = (const float*)d_in[6 + 4 * l];
        const float* A = (l == 0) ? x : hbuf;

        gemm128<<<gemm_blocks, 256, 0, stream>>>(A, W, hW, N);
        agg_relu<<<N, 128, 0, stream>>>(hW, rowp, deg, csr, dinv, b, hbuf, N);
        bn_stats<<<256, 256, 0, stream>>>(hbuf, stats + l * 256, N);
        bn_finalize<<<1, 128, 0, stream>>>(stats + l * 256, g, be, ss + l * 256, 1.0f / N);
        apply_pool<<<pool_blocks, 128, 0, stream>>>(hbuf, ss + l * 256, batch, out, l, N);
    }
}

// Round 3
// 636.051 us; speedup vs baseline: 1.4642x; 1.4642x over previous
//
#include <hip/hip_runtime.h>
#include <hip/hip_bf16.h>

#define N_GRAPHS 128
#define BN_EPS 1e-5f

typedef short bf16x8 __attribute__((ext_vector_type(8)));
typedef short s16x4 __attribute__((ext_vector_type(4)));
typedef float f32x4 __attribute__((ext_vector_type(4)));

__device__ __forceinline__ unsigned short f2b(float f) {   // f32 -> bf16 RNE
    unsigned int u = __builtin_bit_cast(unsigned int, f);
    u += 0x7FFFu + ((u >> 16) & 1u);
    return (unsigned short)(u >> 16);
}
__device__ __forceinline__ float b2f_lo(unsigned int p) {  // low bf16 of packed pair
    return __builtin_bit_cast(float, p << 16);
}
__device__ __forceinline__ float b2f_hi(unsigned int p) {  // high bf16
    return __builtin_bit_cast(float, p & 0xFFFF0000u);
}

// ---------------- preprocessing ----------------

__global__ void hist_kernel(const int* __restrict__ dst, int* __restrict__ cnt, int E) {
    int i = blockIdx.x * blockDim.x + threadIdx.x;
    if (i < E) atomicAdd(&cnt[dst[i]], 1);
}

__global__ void dinv_kernel(const int* __restrict__ cnt, float* __restrict__ dinv, int N) {
    int i = blockIdx.x * blockDim.x + threadIdx.x;
    if (i < N) dinv[i] = rsqrtf((float)(cnt[i] + 1));   // +1 self loop
}

__global__ void scan_partial(const int* __restrict__ cnt, int* __restrict__ out,
                             int* __restrict__ bsums, int n) {
    __shared__ int tmp[256];
    int tid = threadIdx.x;
    int gid = blockIdx.x * 256 + tid;
    int v = (gid < n) ? cnt[gid] : 0;
    tmp[tid] = v;
    __syncthreads();
    for (int off = 1; off < 256; off <<= 1) {
        int t = (tid >= off) ? tmp[tid - off] : 0;
        __syncthreads();
        tmp[tid] += t;
        __syncthreads();
    }
    if (gid < n) out[gid] = tmp[tid] - v;
    if (tid == 255) bsums[blockIdx.x] = tmp[255];
}

__global__ void scan_bsums(int* __restrict__ bsums, int nb) {
    __shared__ int tmp[256];
    int tid = threadIdx.x;
    int v = (tid < nb) ? bsums[tid] : 0;
    tmp[tid] = v;
    __syncthreads();
    for (int off = 1; off < 256; off <<= 1) {
        int t = (tid >= off) ? tmp[tid - off] : 0;
        __syncthreads();
        tmp[tid] += t;
        __syncthreads();
    }
    if (tid < nb) bsums[tid] = tmp[tid] - v;
}

__global__ void scan_add(int* __restrict__ out, const int* __restrict__ bsums, int n) {
    int gid = blockIdx.x * 256 + threadIdx.x;
    if (gid < n) out[gid] += bsums[blockIdx.x];
}

__global__ void fill_csr(const int* __restrict__ src, const int* __restrict__ dst,
                         const int* __restrict__ rowp, int* __restrict__ fill,
                         int* __restrict__ csr, int E) {
    int i = blockIdx.x * blockDim.x + threadIdx.x;
    if (i < E) {
        int dv = dst[i];
        int pos = rowp[dv] + atomicAdd(&fill[dv], 1);
        csr[pos] = src[i];
    }
}

// ---------------- MFMA GEMM: Cb[N,128](bf16) = A[N,128] @ W[128,128] ----------------
// 256 rows/block, 4 waves x 64 rows. W staged in LDS transposed, frag-ordered,
// XOR-swizzled bf16. Swapped operands: mfma(Wfrag, Afrag) yields C^T fragments ->
// 4 consecutive C-cols per lane -> packed 8B bf16 stores.
// frag k-mapping: k = 4*hi + (e&3) + 16*(e>>2), hi = lane>>4.
template <int AF32>
__global__ __launch_bounds__(256) void gemm_mfma(const void* __restrict__ Avoid,
                                                 const float* __restrict__ W,
                                                 unsigned short* __restrict__ Cb, int N) {
    __shared__ unsigned short sWt[128 * 128];
    int tid = threadIdx.x;
    // stage W: linear coalesced read, scalar swizzled LDS writes (one-time)
    for (int i = tid; i < 128 * 128; i += 256) {
        int k = i >> 7, c = i & 127;
        int kk = k & 31, k0 = k >> 5;
        int hi = (kk >> 2) & 3;
        int e = (kk & 3) + 4 * (kk >> 4);
        int idx = c * 128 + k0 * 32 + hi * 8 + e;
        sWt[idx ^ ((c & 7) << 3)] = f2b(W[i]);
    }
    __syncthreads();

    int wave = tid >> 6, lane = tid & 63;
    int lo4 = lane & 15, hi = lane >> 4;
    int rowBase = blockIdx.x * 256 + wave * 64;

    f32x4 acc[8][4];
#pragma unroll
    for (int ct = 0; ct < 8; ++ct)
#pragma unroll
        for (int rt = 0; rt < 4; ++rt) acc[ct][rt] = (f32x4){0.f, 0.f, 0.f, 0.f};

    const float* Af = (const float*)Avoid;
    const unsigned short* Ab = (const unsigned short*)Avoid;

    for (int k0 = 0; k0 < 128; k0 += 32) {
        bf16x8 bfrag[4];
#pragma unroll
        for (int rt = 0; rt < 4; ++rt) {
            int r = rowBase + rt * 16 + lo4;
            if (r >= N) r = N - 1;
            if (AF32) {
                float4 f0 = *(const float4*)(Af + (size_t)r * 128 + k0 + 4 * hi);
                float4 f1 = *(const float4*)(Af + (size_t)r * 128 + k0 + 16 + 4 * hi);
                bf16x8 f;
                f[0] = (short)f2b(f0.x); f[1] = (short)f2b(f0.y);
                f[2] = (short)f2b(f0.z); f[3] = (short)f2b(f0.w);
                f[4] = (short)f2b(f1.x); f[5] = (short)f2b(f1.y);
                f[6] = (short)f2b(f1.z); f[7] = (short)f2b(f1.w);
                bfrag[rt] = f;
            } else {
                s16x4 a0 = *(const s16x4*)(Ab + (size_t)r * 128 + k0 + 4 * hi);
                s16x4 a1 = *(const s16x4*)(Ab + (size_t)r * 128 + k0 + 16 + 4 * hi);
                bf16x8 f;
                f[0] = a0[0]; f[1] = a0[1]; f[2] = a0[2]; f[3] = a0[3];
                f[4] = a1[0]; f[5] = a1[1]; f[6] = a1[2]; f[7] = a1[3];
                bfrag[rt] = f;
            }
        }
        int kq = k0 >> 5;
#pragma unroll
        for (int ct = 0; ct < 8; ++ct) {
            int c = ct * 16 + lo4;
            int idx = (c * 128 + kq * 32 + hi * 8) ^ ((c & 7) << 3);
            bf16x8 af = *(const bf16x8*)(sWt + idx);
#pragma unroll
            for (int rt = 0; rt < 4; ++rt)
                acc[ct][rt] = __builtin_amdgcn_mfma_f32_16x16x32_bf16(af, bfrag[rt], acc[ct][rt], 0, 0, 0);
        }
    }

#pragma unroll
    for (int rt = 0; rt < 4; ++rt) {
        int r = rowBase + rt * 16 + lo4;
        if (r < N) {
#pragma unroll
            for (int ct = 0; ct < 8; ++ct) {
                int c0 = ct * 16 + hi * 4;
                ushort4 s;
                s.x = f2b(acc[ct][rt][0]);
                s.y = f2b(acc[ct][rt][1]);
                s.z = f2b(acc[ct][rt][2]);
                s.w = f2b(acc[ct][rt][3]);
                *(ushort4*)(Cb + (size_t)r * 128 + c0) = s;
            }
        }
    }
}

// ---------------- aggregation + bias + relu: one wave per node, bf16 gather ----------------
__global__ __launch_bounds__(256) void agg_relu_b16(const unsigned int* __restrict__ hW32,
                                                    const int* __restrict__ rowp,
                                                    const int* __restrict__ cnt,
                                                    const int* __restrict__ csr,
                                                    const float* __restrict__ dinv,
                                                    const float* __restrict__ bias,
                                                    float* __restrict__ z, int N) {
    int wave = threadIdx.x >> 6, lane = threadIdx.x & 63;
    int v = blockIdx.x * 4 + wave;
    if (v >= N) return;
    int beg = rowp[v];
    int num = cnt[v];
    float s0 = 0.f, s1 = 0.f;
    int i = 0;
    for (; i + 4 <= num; i += 4) {
        int u0 = csr[beg + i + 0];
        int u1 = csr[beg + i + 1];
        int u2 = csr[beg + i + 2];
        int u3 = csr[beg + i + 3];
        float w0 = dinv[u0], w1 = dinv[u1], w2 = dinv[u2], w3 = dinv[u3];
        unsigned int p0 = hW32[(size_t)u0 * 64 + lane];
        unsigned int p1 = hW32[(size_t)u1 * 64 + lane];
        unsigned int p2 = hW32[(size_t)u2 * 64 + lane];
        unsigned int p3 = hW32[(size_t)u3 * 64 + lane];
        s0 += w0 * b2f_lo(p0) + w1 * b2f_lo(p1) + w2 * b2f_lo(p2) + w3 * b2f_lo(p3);
        s1 += w0 * b2f_hi(p0) + w1 * b2f_hi(p1) + w2 * b2f_hi(p2) + w3 * b2f_hi(p3);
    }
    for (; i < num; ++i) {
        int u = csr[beg + i];
        float w = dinv[u];
        unsigned int p = hW32[(size_t)u * 64 + lane];
        s0 += w * b2f_lo(p);
        s1 += w * b2f_hi(p);
    }
    float dv = dinv[v];
    unsigned int pv = hW32[(size_t)v * 64 + lane];
    s0 = dv * s0 + dv * dv * b2f_lo(pv) + bias[2 * lane];
    s1 = dv * s1 + dv * dv * b2f_hi(pv) + bias[2 * lane + 1];
    float2 o = make_float2(fmaxf(s0, 0.f), fmaxf(s1, 0.f));
    *(float2*)(z + (size_t)v * 128 + 2 * lane) = o;
}

// ---------------- BN statistics ----------------
__global__ __launch_bounds__(256) void bn_stats(const float* __restrict__ z,
                                                float* __restrict__ stats, int N) {
    int d = threadIdx.x & 127;
    int half = threadIdx.x >> 7;
    float sum = 0.f, sq = 0.f;
    for (int v = blockIdx.x * 2 + half; v < N; v += gridDim.x * 2) {
        float x = z[(size_t)v * 128 + d];
        sum += x;
        sq = fmaf(x, x, sq);
    }
    __shared__ float ls[256], lq[256];
    ls[threadIdx.x] = sum;
    lq[threadIdx.x] = sq;
    __syncthreads();
    if (half == 0) {
        atomicAdd(&stats[d], ls[threadIdx.x] + ls[threadIdx.x + 128]);
        atomicAdd(&stats[128 + d], lq[threadIdx.x] + lq[threadIdx.x + 128]);
    }
}

__global__ void bn_finalize(const float* __restrict__ stats, const float* __restrict__ g,
                            const float* __restrict__ be, float* __restrict__ ss, float invN) {
    int d = threadIdx.x;  // 128 threads
    float mu = stats[d] * invN;
    float var = stats[128 + d] * invN - mu * mu;
    float sc = g[d] * rsqrtf(var + BN_EPS);
    ss[d] = sc;
    ss[128 + d] = be[d] - mu * sc;
}

// ---------------- apply BN + pooled segment sum + bf16 write of next input ----------------
__global__ __launch_bounds__(128) void apply_pool(const float* __restrict__ z,
                                                  const float* __restrict__ ss,
                                                  const int* __restrict__ batch,
                                                  float* __restrict__ out,
                                                  unsigned short* __restrict__ zb,
                                                  int layer, int N) {
    __shared__ int gb[32];
    int d = threadIdx.x;
    int v0 = blockIdx.x * 32;
    int vend = min(v0 + 32, N);
    int cntv = vend - v0;
    if (d < cntv) gb[d] = batch[v0 + d];
    __syncthreads();

    float sc = ss[d], sh = ss[128 + d];
    float acc = 0.f;
    int cur = gb[0];
    for (int j = 0; j < cntv; ++j) {
        float val = fmaf(z[(size_t)(v0 + j) * 128 + d], sc, sh);
        if (zb) zb[(size_t)(v0 + j) * 128 + d] = f2b(val);
        int g = gb[j];
        if (g != cur) {
            atomicAdd(&out[(size_t)cur * 384 + layer * 128 + d], acc);
            acc = 0.f;
            cur = g;
        }
        acc += val;
    }
    atomicAdd(&out[(size_t)cur * 384 + layer * 128 + d], acc);
}

// ---------------- launch ----------------
extern "C" void kernel_launch(void* const* d_in, const int* in_sizes, int n_in,
                              void* d_out, int out_size, void* d_ws, size_t ws_size,
                              hipStream_t stream) {
    const float* x    = (const float*)d_in[0];
    const int* eidx   = (const int*)d_in[1];
    const int* batch  = (const int*)d_in[2];

    const int N = in_sizes[2];          // 50000
    const int E = in_sizes[1] / 2;      // 1600000
    const int* src = eidx;
    const int* dst = eidx + E;

    size_t off = 0;
    auto alloc = [&](size_t bytes) {
        void* p = (char*)d_ws + off;
        off += (bytes + 255) & ~(size_t)255;
        return p;
    };
    unsigned short* hWb = (unsigned short*)alloc((size_t)N * 128 * 2);  // bf16 h@W
    unsigned short* zb  = (unsigned short*)alloc((size_t)N * 128 * 2);  // bf16 post-BN (next A)
    float* hbuf  = (float*)alloc((size_t)N * 128 * 4);                  // f32 post-agg (pre-BN)
    int*   csr   = (int*)alloc((size_t)E * 4);
    int*   deg   = (int*)alloc((size_t)N * 4);
    int*   rowp  = (int*)alloc((size_t)N * 4);
    int*   fill  = (int*)alloc((size_t)N * 4);
    float* dinv  = (float*)alloc((size_t)N * 4);
    int*   bsums = (int*)alloc(1024);
    float* stats = (float*)alloc(3 * 256 * 4);
    float* ss    = (float*)alloc(3 * 256 * 4);

    float* out = (float*)d_out;

    hipMemsetAsync(deg, 0, (size_t)N * 4, stream);
    hipMemsetAsync(fill, 0, (size_t)N * 4, stream);
    hipMemsetAsync(stats, 0, 3 * 256 * 4, stream);
    hipMemsetAsync(out, 0, (size_t)N_GRAPHS * 384 * 4, stream);

    int nb = (N + 255) / 256;
    hist_kernel<<<(E + 255) / 256, 256, 0, stream>>>(dst, deg, E);
    dinv_kernel<<<nb, 256, 0, stream>>>(deg, dinv, N);
    scan_partial<<<nb, 256, 0, stream>>>(deg, rowp, bsums, N);
    scan_bsums<<<1, 256, 0, stream>>>(bsums, nb);
    scan_add<<<nb, 256, 0, stream>>>(rowp, bsums, N);
    fill_csr<<<(E + 255) / 256, 256, 0, stream>>>(src, dst, rowp, fill, csr, E);

    const int gemm_blocks = (N + 255) / 256;   // 196
    const int agg_blocks  = (N + 3) / 4;       // 12500
    const int pool_blocks = (N + 31) / 32;     // 1563

    for (int l = 0; l < 3; ++l) {
        const float* W  = (const float*)d_in[3 + 4 * l];
        const float* b  = (const float*)d_in[4 + 4 * l];
        const float* g  = (const float*)d_in[5 + 4 * l];
        const float* be = (const float*)d_in[6 + 4 * l];

        if (l == 0)
            gemm_mfma<1><<<gemm_blocks, 256, 0, stream>>>((const void*)x, W, hWb, N);
        else
            gemm_mfma<0><<<gemm_blocks, 256, 0, stream>>>((const void*)zb, W, hWb, N);

        agg_relu_b16<<<agg_blocks, 256, 0, stream>>>((const unsigned int*)hWb, rowp, deg, csr,
                                                     dinv, b, hbuf, N);
        bn_stats<<<256, 256, 0, stream>>>(hbuf, stats + l * 256, N);
        bn_finalize<<<1, 128, 0, stream>>>(stats + l * 256, g, be, ss + l * 256, 1.0f / N);
        apply_pool<<<pool_blocks, 128, 0, stream>>>(hbuf, ss + l * 256, batch, out,
                                                    (l < 2) ? zb : (unsigned short*)nullptr, l, N);
    }
}

// Round 4
// 525.233 us; speedup vs baseline: 1.7732x; 1.2110x over previous
//
#include <hip/hip_runtime.h>
#include <hip/hip_bf16.h>

#define N_GRAPHS 128
#define BN_EPS 1e-5f
#define CHUNK 8192
#define NBU 512            // padded bucket count (actual NB = ceil(N/128) = 391)
#define CAP 8192           // per-bucket edge capacity (mean 4096, sd ~64)

typedef short bf16x8 __attribute__((ext_vector_type(8)));
typedef short s16x4 __attribute__((ext_vector_type(4)));
typedef float f32x4 __attribute__((ext_vector_type(4)));

__device__ __forceinline__ unsigned short f2b(float f) {   // f32 -> bf16 RNE
    unsigned int u = __builtin_bit_cast(unsigned int, f);
    u += 0x7FFFu + ((u >> 16) & 1u);
    return (unsigned short)(u >> 16);
}
__device__ __forceinline__ float b2f_lo(unsigned int p) {
    return __builtin_bit_cast(float, p << 16);
}
__device__ __forceinline__ float b2f_hi(unsigned int p) {
    return __builtin_bit_cast(float, p & 0xFFFF0000u);
}

// ---------------- K1: per-chunk bucket binning (no global atomics) ----------------
// Each block bins its 8192-edge chunk by dst-bucket into its PRIVATE output region
// (writes land in one XCD's L2 -> ~1x HBM write amplification).
__global__ __launch_bounds__(512) void bin_chunks(const int* __restrict__ src,
                                                  const int* __restrict__ dst,
                                                  unsigned int* __restrict__ bpairs,
                                                  int* __restrict__ cnts,
                                                  int* __restrict__ cbase, int E) {
    __shared__ int lhist[NBU], lscan[NBU], lfill[NBU];
    int tid = threadIdx.x;
    int c0 = blockIdx.x * CHUNK;
    int ecnt = min(CHUNK, E - c0);
    lhist[tid] = 0;
    __syncthreads();
    for (int i = tid; i < ecnt; i += 512)
        atomicAdd(&lhist[((unsigned)dst[c0 + i]) >> 7], 1);
    __syncthreads();
    int orig = lhist[tid];
    lscan[tid] = orig;
    __syncthreads();
    for (int off = 1; off < NBU; off <<= 1) {
        int t = (tid >= off) ? lscan[tid - off] : 0;
        __syncthreads();
        lscan[tid] += t;
        __syncthreads();
    }
    int excl = lscan[tid] - orig;
    cnts[blockIdx.x * NBU + tid] = orig;
    cbase[blockIdx.x * NBU + tid] = excl;
    lfill[tid] = 0;
    __syncthreads();
    lscan[tid] = excl;
    __syncthreads();
    for (int i = tid; i < ecnt; i += 512) {
        int d = dst[c0 + i], s = src[c0 + i];
        int b = ((unsigned)d) >> 7;
        int pos = lscan[b] + atomicAdd(&lfill[b], 1);
        bpairs[c0 + pos] = ((unsigned)(d & 127) << 25) | (unsigned)s;
    }
}

// ---------------- K2: bucket bases (column-sum of cnts + scan) ----------------
__global__ __launch_bounds__(512) void bucket_scan(const int* __restrict__ cnts,
                                                   int* __restrict__ bucket_base, int nchunks) {
    __shared__ int s[NBU];
    int b = threadIdx.x;
    int tot = 0;
    for (int c = 0; c < nchunks; ++c) tot += cnts[c * NBU + b];
    s[b] = tot;
    __syncthreads();
    for (int off = 1; off < NBU; off <<= 1) {
        int t = (b >= off) ? s[b - off] : 0;
        __syncthreads();
        s[b] += t;
        __syncthreads();
    }
    bucket_base[b] = s[b] - tot;   // exclusive; bucket_base[NB] == E
}

// ---------------- K3: per-bucket CSR finalize (coalesced writes) ----------------
__global__ __launch_bounds__(256) void bucket_csr(const unsigned int* __restrict__ bpairs,
                                                  const int* __restrict__ cnts,
                                                  const int* __restrict__ cbase,
                                                  const int* __restrict__ bucket_base,
                                                  int* __restrict__ rowp,
                                                  int* __restrict__ degarr,
                                                  float* __restrict__ dinv,
                                                  int* __restrict__ csr,
                                                  int nchunks, int N) {
    __shared__ unsigned int lpr[CAP];
    __shared__ int lcsr[CAP];
    __shared__ int ccnt[256], cofs[256], cb[256];
    __shared__ int lhist[128], lofs[128], lfill[128];
    int tid = threadIdx.x;
    int b = blockIdx.x;
    int bb = bucket_base[b];
    int total = bucket_base[b + 1] - bb;
    if (total > CAP) total = CAP;

    ccnt[tid] = (tid < nchunks) ? cnts[tid * NBU + b] : 0;
    cb[tid]   = (tid < nchunks) ? cbase[tid * NBU + b] : 0;
    cofs[tid] = ccnt[tid];
    __syncthreads();
    int orig = cofs[tid];
    for (int off = 1; off < 256; off <<= 1) {
        int t = (tid >= off) ? cofs[tid - off] : 0;
        __syncthreads();
        cofs[tid] += t;
        __syncthreads();
    }
    int o = cofs[tid] - orig;             // exclusive offset of this chunk's run
    if (tid < nchunks) {
        int len = ccnt[tid];
        const unsigned int* p = bpairs + (size_t)tid * CHUNK + cb[tid];
        for (int i = 0; i < len; ++i) {
            int q = o + i;
            if (q < CAP) lpr[q] = p[i];
        }
    }
    if (tid < 128) { lhist[tid] = 0; lfill[tid] = 0; }
    __syncthreads();
    for (int i = tid; i < total; i += 256)
        atomicAdd(&lhist[lpr[i] >> 25], 1);
    __syncthreads();
    if (tid < 128) lofs[tid] = lhist[tid];
    __syncthreads();
    for (int off = 1; off < 128; off <<= 1) {
        int t = 0;
        if (tid < 128 && tid >= off) t = lofs[tid - off];
        __syncthreads();
        if (tid < 128) lofs[tid] += t;
        __syncthreads();
    }
    if (tid < 128) {
        int v = b * 128 + tid;
        if (v < N) {
            int dg = lhist[tid];
            degarr[v] = dg;
            rowp[v] = bb + lofs[tid] - dg;
            dinv[v] = rsqrtf((float)(dg + 1));
        }
    }
    __syncthreads();
    for (int i = tid; i < total; i += 256) {
        unsigned int pr = lpr[i];
        int dl = pr >> 25;
        int pos = lofs[dl] - lhist[dl] + atomicAdd(&lfill[dl], 1);
        if (pos < CAP) lcsr[pos] = (int)(pr & 0x1FFFFFFu);
    }
    __syncthreads();
    for (int i = tid; i < total; i += 256) csr[bb + i] = lcsr[i];
}

// ---------------- MFMA GEMM: Cb[N,128](bf16) = A[N,128] @ W[128,128] ----------------
template <int AF32>
__global__ __launch_bounds__(256) void gemm_mfma(const void* __restrict__ Avoid,
                                                 const float* __restrict__ W,
                                                 unsigned short* __restrict__ Cb, int N) {
    __shared__ unsigned short sWt[128 * 128];
    int tid = threadIdx.x;
    for (int i = tid; i < 128 * 128; i += 256) {
        int k = i >> 7, c = i & 127;
        int kk = k & 31, k0 = k >> 5;
        int hi = (kk >> 2) & 3;
        int e = (kk & 3) + 4 * (kk >> 4);
        int idx = c * 128 + k0 * 32 + hi * 8 + e;
        sWt[idx ^ ((c & 7) << 3)] = f2b(W[i]);
    }
    __syncthreads();

    int wave = tid >> 6, lane = tid & 63;
    int lo4 = lane & 15, hi = lane >> 4;
    int rowBase = blockIdx.x * 256 + wave * 64;

    f32x4 acc[8][4];
#pragma unroll
    for (int ct = 0; ct < 8; ++ct)
#pragma unroll
        for (int rt = 0; rt < 4; ++rt) acc[ct][rt] = (f32x4){0.f, 0.f, 0.f, 0.f};

    const float* Af = (const float*)Avoid;
    const unsigned short* Ab = (const unsigned short*)Avoid;

    for (int k0 = 0; k0 < 128; k0 += 32) {
        bf16x8 bfrag[4];
#pragma unroll
        for (int rt = 0; rt < 4; ++rt) {
            int r = rowBase + rt * 16 + lo4;
            if (r >= N) r = N - 1;
            if (AF32) {
                float4 f0 = *(const float4*)(Af + (size_t)r * 128 + k0 + 4 * hi);
                float4 f1 = *(const float4*)(Af + (size_t)r * 128 + k0 + 16 + 4 * hi);
                bf16x8 f;
                f[0] = (short)f2b(f0.x); f[1] = (short)f2b(f0.y);
                f[2] = (short)f2b(f0.z); f[3] = (short)f2b(f0.w);
                f[4] = (short)f2b(f1.x); f[5] = (short)f2b(f1.y);
                f[6] = (short)f2b(f1.z); f[7] = (short)f2b(f1.w);
                bfrag[rt] = f;
            } else {
                s16x4 a0 = *(const s16x4*)(Ab + (size_t)r * 128 + k0 + 4 * hi);
                s16x4 a1 = *(const s16x4*)(Ab + (size_t)r * 128 + k0 + 16 + 4 * hi);
                bf16x8 f;
                f[0] = a0[0]; f[1] = a0[1]; f[2] = a0[2]; f[3] = a0[3];
                f[4] = a1[0]; f[5] = a1[1]; f[6] = a1[2]; f[7] = a1[3];
                bfrag[rt] = f;
            }
        }
        int kq = k0 >> 5;
#pragma unroll
        for (int ct = 0; ct < 8; ++ct) {
            int c = ct * 16 + lo4;
            int idx = (c * 128 + kq * 32 + hi * 8) ^ ((c & 7) << 3);
            bf16x8 af = *(const bf16x8*)(sWt + idx);
#pragma unroll
            for (int rt = 0; rt < 4; ++rt)
                acc[ct][rt] = __builtin_amdgcn_mfma_f32_16x16x32_bf16(af, bfrag[rt], acc[ct][rt], 0, 0, 0);
        }
    }

#pragma unroll
    for (int rt = 0; rt < 4; ++rt) {
        int r = rowBase + rt * 16 + lo4;
        if (r < N) {
#pragma unroll
            for (int ct = 0; ct < 8; ++ct) {
                int c0 = ct * 16 + hi * 4;
                ushort4 s;
                s.x = f2b(acc[ct][rt][0]);
                s.y = f2b(acc[ct][rt][1]);
                s.z = f2b(acc[ct][rt][2]);
                s.w = f2b(acc[ct][rt][3]);
                *(ushort4*)(Cb + (size_t)r * 128 + c0) = s;
            }
        }
    }
}

// ---------------- aggregation + bias + relu: one wave per node, bf16 in/out ----------------
__global__ __launch_bounds__(256) void agg_relu_b16(const unsigned int* __restrict__ hW32,
                                                    const int* __restrict__ rowp,
                                                    const int* __restrict__ cnt,
                                                    const int* __restrict__ csr,
                                                    const float* __restrict__ dinv,
                                                    const float* __restrict__ bias,
                                                    unsigned int* __restrict__ z32, int N) {
    int wave = threadIdx.x >> 6, lane = threadIdx.x & 63;
    int v = blockIdx.x * 4 + wave;
    if (v >= N) return;
    int beg = rowp[v];
    int num = cnt[v];
    float s0 = 0.f, s1 = 0.f;
    int i = 0;
    for (; i + 4 <= num; i += 4) {
        int u0 = csr[beg + i + 0];
        int u1 = csr[beg + i + 1];
        int u2 = csr[beg + i + 2];
        int u3 = csr[beg + i + 3];
        float w0 = dinv[u0], w1 = dinv[u1], w2 = dinv[u2], w3 = dinv[u3];
        unsigned int p0 = hW32[(size_t)u0 * 64 + lane];
        unsigned int p1 = hW32[(size_t)u1 * 64 + lane];
        unsigned int p2 = hW32[(size_t)u2 * 64 + lane];
        unsigned int p3 = hW32[(size_t)u3 * 64 + lane];
        s0 += w0 * b2f_lo(p0) + w1 * b2f_lo(p1) + w2 * b2f_lo(p2) + w3 * b2f_lo(p3);
        s1 += w0 * b2f_hi(p0) + w1 * b2f_hi(p1) + w2 * b2f_hi(p2) + w3 * b2f_hi(p3);
    }
    for (; i < num; ++i) {
        int u = csr[beg + i];
        float w = dinv[u];
        unsigned int p = hW32[(size_t)u * 64 + lane];
        s0 += w * b2f_lo(p);
        s1 += w * b2f_hi(p);
    }
    float dv = dinv[v];
    unsigned int pv = hW32[(size_t)v * 64 + lane];
    s0 = dv * s0 + dv * dv * b2f_lo(pv) + bias[2 * lane];
    s1 = dv * s1 + dv * dv * b2f_hi(pv) + bias[2 * lane + 1];
    unsigned int po = (unsigned int)f2b(fmaxf(s0, 0.f)) | ((unsigned int)f2b(fmaxf(s1, 0.f)) << 16);
    z32[(size_t)v * 64 + lane] = po;
}

// ---------------- BN statistics (bf16 input) ----------------
__global__ __launch_bounds__(256) void bn_stats_b16(const unsigned int* __restrict__ z32,
                                                    float* __restrict__ stats, int N) {
    int lane = threadIdx.x & 63, sub = threadIdx.x >> 6;
    float s0 = 0.f, s1 = 0.f, q0 = 0.f, q1 = 0.f;
    for (int v = blockIdx.x * 4 + sub; v < N; v += gridDim.x * 4) {
        unsigned int p = z32[(size_t)v * 64 + lane];
        float a = b2f_lo(p), c = b2f_hi(p);
        s0 += a; q0 = fmaf(a, a, q0);
        s1 += c; q1 = fmaf(c, c, q1);
    }
    __shared__ float ls[256][4];
    ls[threadIdx.x][0] = s0; ls[threadIdx.x][1] = s1;
    ls[threadIdx.x][2] = q0; ls[threadIdx.x][3] = q1;
    __syncthreads();
    if (sub == 0) {
        for (int k = 1; k < 4; ++k) {
            s0 += ls[lane + 64 * k][0]; s1 += ls[lane + 64 * k][1];
            q0 += ls[lane + 64 * k][2]; q1 += ls[lane + 64 * k][3];
        }
        atomicAdd(&stats[2 * lane], s0);
        atomicAdd(&stats[2 * lane + 1], s1);
        atomicAdd(&stats[128 + 2 * lane], q0);
        atomicAdd(&stats[129 + 2 * lane], q1);
    }
}

__global__ void bn_finalize(const float* __restrict__ stats, const float* __restrict__ g,
                            const float* __restrict__ be, float* __restrict__ ss, float invN) {
    int d = threadIdx.x;  // 128 threads
    float mu = stats[d] * invN;
    float var = stats[128 + d] * invN - mu * mu;
    float sc = g[d] * rsqrtf(var + BN_EPS);
    ss[d] = sc;
    ss[128 + d] = be[d] - mu * sc;
}

// ---------------- apply BN + pooled segment sum + bf16 next-input write ----------------
__global__ __launch_bounds__(64) void apply_pool_b16(const unsigned int* __restrict__ z32,
                                                     const float* __restrict__ ss,
                                                     const int* __restrict__ batch,
                                                     float* __restrict__ out,
                                                     unsigned int* __restrict__ zb,
                                                     int layer, int N) {
    __shared__ int gb[32];
    int lane = threadIdx.x;
    int v0 = blockIdx.x * 32;
    int vend = min(v0 + 32, N);
    int cntv = vend - v0;
    if (lane < cntv) gb[lane] = batch[v0 + lane];
    __syncthreads();
    float sc0 = ss[2 * lane], sc1 = ss[2 * lane + 1];
    float sh0 = ss[128 + 2 * lane], sh1 = ss[129 + 2 * lane];
    float a0 = 0.f, a1 = 0.f;
    int cur = gb[0];
    for (int j = 0; j < cntv; ++j) {
        unsigned int p = z32[(size_t)(v0 + j) * 64 + lane];
        float x0 = fmaf(b2f_lo(p), sc0, sh0);
        float x1 = fmaf(b2f_hi(p), sc1, sh1);
        if (zb) zb[(size_t)(v0 + j) * 64 + lane] =
            (unsigned int)f2b(x0) | ((unsigned int)f2b(x1) << 16);
        int g = gb[j];
        if (g != cur) {
            atomicAdd(&out[(size_t)cur * 384 + layer * 128 + 2 * lane], a0);
            atomicAdd(&out[(size_t)cur * 384 + layer * 128 + 2 * lane + 1], a1);
            a0 = a1 = 0.f;
            cur = g;
        }
        a0 += x0; a1 += x1;
    }
    atomicAdd(&out[(size_t)cur * 384 + layer * 128 + 2 * lane], a0);
    atomicAdd(&out[(size_t)cur * 384 + layer * 128 + 2 * lane + 1], a1);
}

// ---------------- launch ----------------
extern "C" void kernel_launch(void* const* d_in, const int* in_sizes, int n_in,
                              void* d_out, int out_size, void* d_ws, size_t ws_size,
                              hipStream_t stream) {
    const float* x    = (const float*)d_in[0];
    const int* eidx   = (const int*)d_in[1];
    const int* batch  = (const int*)d_in[2];

    const int N = in_sizes[2];          // 50000
    const int E = in_sizes[1] / 2;      // 1600000
    const int* src = eidx;
    const int* dst = eidx + E;

    const int nchunks = (E + CHUNK - 1) / CHUNK;   // 196
    const int NB = (N + 127) / 128;                // 391

    size_t off = 0;
    auto alloc = [&](size_t bytes) {
        void* p = (char*)d_ws + off;
        off += (bytes + 255) & ~(size_t)255;
        return p;
    };
    unsigned short* hWb = (unsigned short*)alloc((size_t)N * 128 * 2);  // bf16 h@W
    unsigned int* zb    = (unsigned int*)alloc((size_t)N * 64 * 4);     // bf16 post-BN (next A)
    unsigned int* z32   = (unsigned int*)alloc((size_t)N * 64 * 4);     // bf16 post-agg
    unsigned int* bpairs= (unsigned int*)alloc((size_t)nchunks * CHUNK * 4);
    int*   csr   = (int*)alloc((size_t)E * 4);
    int*   cnts  = (int*)alloc((size_t)nchunks * NBU * 4);
    int*   cbase = (int*)alloc((size_t)nchunks * NBU * 4);
    int*   bbase = (int*)alloc((size_t)(NBU + 1) * 4);
    int*   degar = (int*)alloc((size_t)N * 4);
    int*   rowp  = (int*)alloc((size_t)N * 4);
    float* dinv  = (float*)alloc((size_t)N * 4);
    float* stats = (float*)alloc(3 * 256 * 4);
    float* ss    = (float*)alloc(3 * 256 * 4);

    float* out = (float*)d_out;

    hipMemsetAsync(stats, 0, 3 * 256 * 4, stream);
    hipMemsetAsync(out, 0, (size_t)N_GRAPHS * 384 * 4, stream);

    bin_chunks<<<nchunks, 512, 0, stream>>>(src, dst, bpairs, cnts, cbase, E);
    bucket_scan<<<1, 512, 0, stream>>>(cnts, bbase, nchunks);
    bucket_csr<<<NB, 256, 0, stream>>>(bpairs, cnts, cbase, bbase, rowp, degar, dinv, csr,
                                       nchunks, N);

    const int gemm_blocks = (N + 255) / 256;   // 196
    const int agg_blocks  = (N + 3) / 4;       // 12500
    const int pool_blocks = (N + 31) / 32;     // 1563

    for (int l = 0; l < 3; ++l) {
        const float* W  = (const float*)d_in[3 + 4 * l];
        const float* b  = (const float*)d_in[4 + 4 * l];
        const float* g  = (const float*)d_in[5 + 4 * l];
        const float* be = (const float*)d_in[6 + 4 * l];

        if (l == 0)
            gemm_mfma<1><<<gemm_blocks, 256, 0, stream>>>((const void*)x, W, hWb, N);
        else
            gemm_mfma<0><<<gemm_blocks, 256, 0, stream>>>((const void*)zb, W, hWb, N);

        agg_relu_b16<<<agg_blocks, 256, 0, stream>>>((const unsigned int*)hWb, rowp, degar, csr,
                                                     dinv, b, z32, N);
        bn_stats_b16<<<256, 256, 0, stream>>>(z32, stats + l * 256, N);
        bn_finalize<<<1, 128, 0, stream>>>(stats + l * 256, g, be, ss + l * 256, 1.0f / N);
        apply_pool_b16<<<pool_blocks, 64, 0, stream>>>(z32, ss + l * 256, batch, out,
                                                       (l < 2) ? zb : (unsigned int*)nullptr, l, N);
    }
}